// Round 3
// baseline (3191.978 us; speedup 1.0000x reference)
//
#include <hip/hip_runtime.h>
#include <math.h>

// ---------------- constants (shapes fixed by the reference) ----------------
#define IN_CH   256
#define HC      256   // H*C
#define H_HEADS 4
#define NEG_SLOPE 0.2f

typedef __attribute__((ext_vector_type(8))) short short8;
typedef __attribute__((ext_vector_type(4))) float float4v;

// ---------------- helpers ----------------
__device__ __forceinline__ float bf2f(unsigned short b) {
    return __uint_as_float(((unsigned)b) << 16);
}
__device__ __forceinline__ unsigned short f2bf(float f) {
    unsigned u = __float_as_uint(f);
    u += 0x7fffu + ((u >> 16) & 1u);    // round-to-nearest-even
    return (unsigned short)(u >> 16);
}
// monotone float<->uint encoding for atomicMax-based segment max.
// memset-0 init decodes below every finite float's key; unused slots never read.
__device__ __forceinline__ unsigned enc_f(float f) {
    int i = __float_as_int(f);
    return (i >= 0) ? ((unsigned)i | 0x80000000u) : (unsigned)(~i);
}
__device__ __forceinline__ float dec_f(unsigned u) {
    int i = (u & 0x80000000u) ? (int)(u & 0x7fffffffu) : (int)(~u);
    return __int_as_float(i);
}
__device__ __forceinline__ float lrelu(float a) {
    return a >= 0.f ? a : NEG_SLOPE * a;
}

// ---------------- kernels ----------------

// W (fp32, 256x256 row-major, W[k][c]) -> transposed bf16 hi/lo pair:
// wt_hi[c][k] + wt_lo[c][k], so B-fragments load as contiguous 16B shorts.
__global__ void prep_w(const float* __restrict__ w,
                       unsigned short* __restrict__ wt_hi,
                       unsigned short* __restrict__ wt_lo) {
    int idx = blockIdx.x * 256 + threadIdx.x;   // 65536 total
    int k = idx >> 8, c = idx & 255;
    float v = w[idx];
    unsigned short hi = f2bf(v);
    unsigned short lo = f2bf(v - bf2f(hi));
    wt_hi[(size_t)c * 256 + k] = hi;
    wt_lo[(size_t)c * 256 + k] = lo;
}

// xh = x @ W  (fp32 in/out; bf16 hi/lo split -> 3 MFMAs per fragment pair,
// relative error ~2^-16). block = 4 waves; tile 64 rows x 64 cols.
__global__ __launch_bounds__(256) void gemm_xh(const float* __restrict__ x,
                                               const unsigned short* __restrict__ wt_hi,
                                               const unsigned short* __restrict__ wt_lo,
                                               float* __restrict__ xh, int N) {
    int wave = threadIdx.x >> 6;
    int lane = threadIdx.x & 63;
    int quad = lane >> 4;
    int l16  = lane & 15;
    int rb = blockIdx.x * 64 + wave * 16;
    int cb = blockIdx.y * 64;

    float4v acc[4] = {};
    int arow = rb + l16;                // A[m=lane&15][k=quad*8+j]
    if (arow >= N) arow = N - 1;        // clamp (stores guarded below)
    const float* xrow = x + (size_t)arow * IN_CH;

    for (int k0 = 0; k0 < IN_CH; k0 += 32) {
        float4v xa = *(const float4v*)(xrow + k0 + quad * 8);
        float4v xb = *(const float4v*)(xrow + k0 + quad * 8 + 4);
        short8 a_hi, a_lo;
#pragma unroll
        for (int j = 0; j < 4; ++j) {
            unsigned short h0 = f2bf(xa[j]);
            a_hi[j]     = (short)h0;
            a_lo[j]     = (short)f2bf(xa[j] - bf2f(h0));
            unsigned short h1 = f2bf(xb[j]);
            a_hi[4 + j] = (short)h1;
            a_lo[4 + j] = (short)f2bf(xb[j] - bf2f(h1));
        }
#pragma unroll
        for (int ct = 0; ct < 4; ++ct) {
            int col = cb + ct * 16 + l16;   // B[k][n=lane&15] from W^T[col][k]
            const size_t bo = (size_t)col * IN_CH + k0 + quad * 8;
            short8 bh = *(const short8*)(wt_hi + bo);
            short8 bl = *(const short8*)(wt_lo + bo);
            acc[ct] = __builtin_amdgcn_mfma_f32_16x16x32_bf16(a_lo, bh, acc[ct], 0, 0, 0);
            acc[ct] = __builtin_amdgcn_mfma_f32_16x16x32_bf16(a_hi, bl, acc[ct], 0, 0, 0);
            acc[ct] = __builtin_amdgcn_mfma_f32_16x16x32_bf16(a_hi, bh, acc[ct], 0, 0, 0);
        }
    }
    // C/D: row = quad*4 + r, col = lane&15
#pragma unroll
    for (int ct = 0; ct < 4; ++ct) {
#pragma unroll
        for (int r = 0; r < 4; ++r) {
            int grow = rb + quad * 4 + r;
            if (grow < N)
                xh[(size_t)grow * HC + cb + ct * 16 + l16] = acc[ct][r];
        }
    }
}

// a_src[n,h] = sum_c xh[n,h,c]*att_src[h,c]; same for a_dst. One wave per node.
// flat channel f = lane*4+j == h*64 + (lane&15)*4 + j, h = lane>>4
__global__ __launch_bounds__(256) void node_attn(const float* __restrict__ xh,
                                                 const float* __restrict__ att_s,
                                                 const float* __restrict__ att_d,
                                                 float* __restrict__ a_src,
                                                 float* __restrict__ a_dst, int N) {
    int wave = threadIdx.x >> 6, lane = threadIdx.x & 63;
    int n = blockIdx.x * 4 + wave;
    if (n >= N) return;
    int h = lane >> 4;
    float4v xv = *(const float4v*)(xh + (size_t)n * HC + lane * 4);
    float4v as = *(const float4v*)(att_s + lane * 4);
    float4v ad = *(const float4v*)(att_d + lane * 4);
    float ss = 0.f, sd = 0.f;
#pragma unroll
    for (int j = 0; j < 4; ++j) {
        ss += xv[j] * as[j];
        sd += xv[j] * ad[j];
    }
#pragma unroll
    for (int off = 1; off < 16; off <<= 1) {
        ss += __shfl_xor(ss, off);
        sd += __shfl_xor(sd, off);
    }
    if ((lane & 15) == 0) {
        a_src[n * H_HEADS + h] = ss;
        a_dst[n * H_HEADS + h] = sd;
    }
}

// segment max of leakyrelu(a_src[src]+a_dst[dst]) over dst, via encoded atomicMax
__global__ __launch_bounds__(256) void edge_max(const int* __restrict__ ei,
                                                const float* __restrict__ a_src,
                                                const float* __restrict__ a_dst,
                                                unsigned* __restrict__ mkey, int E) {
    int e = blockIdx.x * 256 + threadIdx.x;
    if (e >= E) return;
    int s = ei[e], d = ei[E + e];
    float4v as = *(const float4v*)(a_src + (size_t)s * 4);
    float4v ad = *(const float4v*)(a_dst + (size_t)d * 4);
#pragma unroll
    for (int h = 0; h < 4; ++h)
        atomicMax(mkey + (size_t)d * 4 + h, enc_f(lrelu(as[h] + ad[h])));
}

// denom[n,h] = sum exp(alpha - m) over incoming edges
__global__ __launch_bounds__(256) void edge_exp(const int* __restrict__ ei,
                                                const float* __restrict__ a_src,
                                                const float* __restrict__ a_dst,
                                                const unsigned* __restrict__ mkey,
                                                float* __restrict__ denom, int E) {
    int e = blockIdx.x * 256 + threadIdx.x;
    if (e >= E) return;
    int s = ei[e], d = ei[E + e];
    float4v as = *(const float4v*)(a_src + (size_t)s * 4);
    float4v ad = *(const float4v*)(a_dst + (size_t)d * 4);
#pragma unroll
    for (int h = 0; h < 4; ++h) {
        float m = dec_f(mkey[(size_t)d * 4 + h]);
        unsafeAtomicAdd(denom + (size_t)d * 4 + h, expf(lrelu(as[h] + ad[h]) - m));
    }
}

// att = exp(alpha-m)/(denom+eps); write att (fp32) and scatter att*xh[src] into
// fp32 output. One wave per edge; lane owns flat channels [lane*4, lane*4+4).
__global__ __launch_bounds__(256) void edge_att_scatter(const int* __restrict__ ei,
                                                        const float* __restrict__ a_src,
                                                        const float* __restrict__ a_dst,
                                                        const unsigned* __restrict__ mkey,
                                                        const float* __restrict__ denom,
                                                        const float* __restrict__ xh,
                                                        float* __restrict__ out,
                                                        float* __restrict__ att_out,
                                                        int E) {
    int wave = threadIdx.x >> 6, lane = threadIdx.x & 63;
    int e = blockIdx.x * 4 + wave;
    if (e >= E) return;
    int s = ei[e], d = ei[E + e];
    int h = lane >> 4;
    float al = lrelu(a_src[(size_t)s * 4 + h] + a_dst[(size_t)d * 4 + h]);
    float m  = dec_f(mkey[(size_t)d * 4 + h]);
    float den = denom[(size_t)d * 4 + h];
    float att = expf(al - m) / (den + 1e-16f);
    if ((lane & 15) == 0)
        att_out[(size_t)e * 4 + h] = att;
    float4v xv = *(const float4v*)(xh + (size_t)s * HC + lane * 4);
    float* ob = out + (size_t)d * HC + lane * 4;
#pragma unroll
    for (int j = 0; j < 4; ++j)
        unsafeAtomicAdd(ob + j, att * xv[j]);
}

// ---------------- launcher ----------------
extern "C" void kernel_launch(void* const* d_in, const int* in_sizes, int n_in,
                              void* d_out, int out_size, void* d_ws, size_t ws_size,
                              hipStream_t stream) {
    const float* x     = (const float*)d_in[0];  // fp32 [N,256]
    const int*   ei    = (const int*)d_in[1];    // int32 [2,E]
    const float* W     = (const float*)d_in[2];  // fp32 [256,256]
    const float* att_s = (const float*)d_in[3];  // fp32 [4,64]
    const float* att_d = (const float*)d_in[4];  // fp32 [4,64]

    const int N = in_sizes[0] / IN_CH;   // 50000
    const int E = in_sizes[1] / 2;       // 800000

    char* ws = (char*)d_ws;
    size_t off = 0;
    float*          xh    = (float*)(ws + off);          off += (size_t)N * HC * 4;
    unsigned short* wt_hi = (unsigned short*)(ws + off); off += (size_t)IN_CH * HC * 2;
    unsigned short* wt_lo = (unsigned short*)(ws + off); off += (size_t)IN_CH * HC * 2;
    float* a_src = (float*)(ws + off); off += (size_t)N * H_HEADS * 4;
    float* a_dst = (float*)(ws + off); off += (size_t)N * H_HEADS * 4;
    size_t zoff = off;  // zero-init region starts here
    unsigned* mkey  = (unsigned*)(ws + off); off += (size_t)N * H_HEADS * 4;
    float*    denom = (float*)(ws + off);    off += (size_t)N * H_HEADS * 4;

    float* out     = (float*)d_out;            // [N, 256] fp32
    float* out_att = out + (size_t)N * HC;     // [E, 4]   fp32

    // harness re-poisons d_out/d_ws with 0xAA before every replay:
    // zero the scatter accumulator (= out itself) and max/denom each call.
    hipMemsetAsync(out, 0, (size_t)N * HC * 4, stream);
    hipMemsetAsync(ws + zoff, 0, off - zoff, stream);

    prep_w<<<256, 256, 0, stream>>>(W, wt_hi, wt_lo);
    gemm_xh<<<dim3((N + 63) / 64, 4), 256, 0, stream>>>(x, wt_hi, wt_lo, xh, N);
    node_attn<<<(N + 3) / 4, 256, 0, stream>>>(xh, att_s, att_d, a_src, a_dst, N);
    edge_max<<<(E + 255) / 256, 256, 0, stream>>>(ei, a_src, a_dst, mkey, E);
    edge_exp<<<(E + 255) / 256, 256, 0, stream>>>(ei, a_src, a_dst, mkey, denom, E);
    edge_att_scatter<<<(E + 3) / 4, 256, 0, stream>>>(ei, a_src, a_dst, mkey, denom,
                                                      xh, out, out_att, E);
}

// Round 4
// 574.796 us; speedup vs baseline: 5.5532x; 5.5532x over previous
//
#include <hip/hip_runtime.h>
#include <math.h>

// ---------------- constants (shapes fixed by the reference) ----------------
#define IN_CH   256
#define HC      256   // H*C
#define H_HEADS 4
#define NEG_SLOPE 0.2f
#define SCAN_T  1024

typedef __attribute__((ext_vector_type(8))) short short8;
typedef __attribute__((ext_vector_type(4))) float float4v;

// ---------------- helpers ----------------
__device__ __forceinline__ float bf2f(unsigned short b) {
    return __uint_as_float(((unsigned)b) << 16);
}
__device__ __forceinline__ unsigned short f2bf(float f) {
    unsigned u = __float_as_uint(f);
    u += 0x7fffu + ((u >> 16) & 1u);    // round-to-nearest-even
    return (unsigned short)(u >> 16);
}
__device__ __forceinline__ float lrelu(float a) {
    return a >= 0.f ? a : NEG_SLOPE * a;
}

// ---------------- kernels ----------------

// W (fp32, [256k x 256c] row-major) -> transposed bf16 hi/lo pair (wt[c][k])
__global__ void prep_w(const float* __restrict__ w,
                       unsigned short* __restrict__ wt_hi,
                       unsigned short* __restrict__ wt_lo) {
    int idx = blockIdx.x * 256 + threadIdx.x;   // 65536 total
    int k = idx >> 8, c = idx & 255;
    float v = w[idx];
    unsigned short hi = f2bf(v);
    unsigned short lo = f2bf(v - bf2f(hi));
    wt_hi[(size_t)c * 256 + k] = hi;
    wt_lo[(size_t)c * 256 + k] = lo;
}

// xh = x @ W  (fp32 in/out; bf16 hi/lo split -> 3 MFMAs, rel err ~2^-16)
__global__ __launch_bounds__(256) void gemm_xh(const float* __restrict__ x,
                                               const unsigned short* __restrict__ wt_hi,
                                               const unsigned short* __restrict__ wt_lo,
                                               float* __restrict__ xh, int N) {
    int wave = threadIdx.x >> 6;
    int lane = threadIdx.x & 63;
    int quad = lane >> 4;
    int l16  = lane & 15;
    int rb = blockIdx.x * 64 + wave * 16;
    int cb = blockIdx.y * 64;

    float4v acc[4] = {};
    int arow = rb + l16;                // A[m=lane&15][k=quad*8+j]
    if (arow >= N) arow = N - 1;        // clamp (stores guarded below)
    const float* xrow = x + (size_t)arow * IN_CH;

    for (int k0 = 0; k0 < IN_CH; k0 += 32) {
        float4v xa = *(const float4v*)(xrow + k0 + quad * 8);
        float4v xb = *(const float4v*)(xrow + k0 + quad * 8 + 4);
        short8 a_hi, a_lo;
#pragma unroll
        for (int j = 0; j < 4; ++j) {
            unsigned short h0 = f2bf(xa[j]);
            a_hi[j]     = (short)h0;
            a_lo[j]     = (short)f2bf(xa[j] - bf2f(h0));
            unsigned short h1 = f2bf(xb[j]);
            a_hi[4 + j] = (short)h1;
            a_lo[4 + j] = (short)f2bf(xb[j] - bf2f(h1));
        }
#pragma unroll
        for (int ct = 0; ct < 4; ++ct) {
            int col = cb + ct * 16 + l16;   // B[k][n=lane&15] from W^T[col][k]
            const size_t bo = (size_t)col * IN_CH + k0 + quad * 8;
            short8 bh = *(const short8*)(wt_hi + bo);
            short8 bl = *(const short8*)(wt_lo + bo);
            acc[ct] = __builtin_amdgcn_mfma_f32_16x16x32_bf16(a_lo, bh, acc[ct], 0, 0, 0);
            acc[ct] = __builtin_amdgcn_mfma_f32_16x16x32_bf16(a_hi, bl, acc[ct], 0, 0, 0);
            acc[ct] = __builtin_amdgcn_mfma_f32_16x16x32_bf16(a_hi, bh, acc[ct], 0, 0, 0);
        }
    }
    // C/D: row = quad*4 + r, col = lane&15
#pragma unroll
    for (int ct = 0; ct < 4; ++ct) {
#pragma unroll
        for (int r = 0; r < 4; ++r) {
            int grow = rb + quad * 4 + r;
            if (grow < N)
                xh[(size_t)grow * HC + cb + ct * 16 + l16] = acc[ct][r];
        }
    }
}

// a_src[n,h] = sum_c xh[n,h,c]*att_src[h,c]; same for a_dst. One wave per node.
__global__ __launch_bounds__(256) void node_attn(const float* __restrict__ xh,
                                                 const float* __restrict__ att_s,
                                                 const float* __restrict__ att_d,
                                                 float* __restrict__ a_src,
                                                 float* __restrict__ a_dst, int N) {
    int wave = threadIdx.x >> 6, lane = threadIdx.x & 63;
    int n = blockIdx.x * 4 + wave;
    if (n >= N) return;
    int h = lane >> 4;
    float4v xv = *(const float4v*)(xh + (size_t)n * HC + lane * 4);
    float4v as = *(const float4v*)(att_s + lane * 4);
    float4v ad = *(const float4v*)(att_d + lane * 4);
    float ss = 0.f, sd = 0.f;
#pragma unroll
    for (int j = 0; j < 4; ++j) {
        ss += xv[j] * as[j];
        sd += xv[j] * ad[j];
    }
#pragma unroll
    for (int off = 1; off < 16; off <<= 1) {
        ss += __shfl_xor(ss, off);
        sd += __shfl_xor(sd, off);
    }
    if ((lane & 15) == 0) {
        a_src[n * H_HEADS + h] = ss;
        a_dst[n * H_HEADS + h] = sd;
    }
}

// degree histogram over dst
__global__ __launch_bounds__(256) void deg_count(const int* __restrict__ ei,
                                                 int* __restrict__ deg, int E) {
    int e = blockIdx.x * 256 + threadIdx.x;
    if (e >= E) return;
    atomicAdd(deg + ei[E + e], 1);
}

// single-block exclusive scan of deg[N] -> rowptr, cursor
__global__ __launch_bounds__(SCAN_T) void scan_rowptr(const int* __restrict__ deg,
                                                      int* __restrict__ rowptr,
                                                      int* __restrict__ cursor, int N) {
    __shared__ int part[SCAN_T];
    int t = threadIdx.x;
    int chunk = (N + SCAN_T - 1) / SCAN_T;
    int lo = t * chunk, hi = min(lo + chunk, N);
    int s = 0;
    for (int i = lo; i < hi; ++i) s += deg[i];
    part[t] = s;
    __syncthreads();
    // Hillis-Steele inclusive scan over 1024 partials
    for (int off = 1; off < SCAN_T; off <<= 1) {
        int tmp = (t >= off) ? part[t - off] : 0;
        __syncthreads();
        part[t] += tmp;
        __syncthreads();
    }
    int running = part[t] - s;   // exclusive prefix of this chunk
    for (int i = lo; i < hi; ++i) {
        rowptr[i] = running;
        cursor[i] = running;
        running += deg[i];
    }
}

// fill CSR: csr_src[slot] = src id, slots allocated per-dst via cursor atomics
__global__ __launch_bounds__(256) void fill_csr(const int* __restrict__ ei,
                                                int* __restrict__ cursor,
                                                int* __restrict__ csr_src, int E) {
    int e = blockIdx.x * 256 + threadIdx.x;
    if (e >= E) return;
    int s = ei[e], d = ei[E + e];
    int slot = atomicAdd(cursor + d, 1);
    csr_src[slot] = s;
}

// one wave per dst node: online-softmax gather over incoming edges.
// lane owns flat channels [lane*4, lane*4+4); head h = lane>>4.
// Writes out[d] (256 fp32) + per-(d,h) final max m and denom l.
__global__ __launch_bounds__(256) void gat_gather(const int* __restrict__ csr_src,
                                                  const int* __restrict__ rowptr,
                                                  const int* __restrict__ deg,
                                                  const float* __restrict__ a_src,
                                                  const float* __restrict__ a_dst,
                                                  const float* __restrict__ xh,
                                                  float* __restrict__ out,
                                                  float* __restrict__ mfin,
                                                  float* __restrict__ lfin, int N) {
    int wave = threadIdx.x >> 6, lane = threadIdx.x & 63;
    int d = blockIdx.x * 4 + wave;
    if (d >= N) return;
    int h = lane >> 4;
    int start = rowptr[d], cnt = deg[d];
    float adst = a_dst[(size_t)d * 4 + h];

    float m = -INFINITY, l = 0.f;
    float4v acc = {0.f, 0.f, 0.f, 0.f};

    // double-buffered prefetch of (src, a_src, xh row)
    int s_n = 0; float as_n = 0.f; float4v xv_n = {};
    if (cnt > 0) {
        s_n  = csr_src[start];
        as_n = a_src[(size_t)s_n * 4 + h];
        xv_n = *(const float4v*)(xh + (size_t)s_n * HC + lane * 4);
    }
    for (int i = 0; i < cnt; ++i) {
        float as_c = as_n; float4v xv = xv_n;
        if (i + 1 < cnt) {
            s_n  = csr_src[start + i + 1];
            as_n = a_src[(size_t)s_n * 4 + h];
            xv_n = *(const float4v*)(xh + (size_t)s_n * HC + lane * 4);
        }
        float al = lrelu(as_c + adst);
        float mn = fmaxf(m, al);
        float scale = __expf(m - mn);   // first iter: exp(-inf)=0
        float p     = __expf(al - mn);
        l = l * scale + p;
#pragma unroll
        for (int j = 0; j < 4; ++j) acc[j] = acc[j] * scale + p * xv[j];
        m = mn;
    }
    float inv = 1.f / (l + 1e-16f);
    float4v o = {acc[0] * inv, acc[1] * inv, acc[2] * inv, acc[3] * inv};
    *(float4v*)(out + (size_t)d * HC + lane * 4) = o;
    if ((lane & 15) == 0) {
        mfin[(size_t)d * 4 + h] = m;
        lfin[(size_t)d * 4 + h] = l;
    }
}

// att[e,h] = exp(alpha - m[d,h]) / (l[d,h] + eps)
__global__ __launch_bounds__(256) void att_edge(const int* __restrict__ ei,
                                                const float* __restrict__ a_src,
                                                const float* __restrict__ a_dst,
                                                const float* __restrict__ mfin,
                                                const float* __restrict__ lfin,
                                                float* __restrict__ att_out, int E4) {
    int idx = blockIdx.x * 256 + threadIdx.x;
    if (idx >= E4) return;
    int e = idx >> 2, h = idx & 3;
    int E = E4 >> 2;
    int s = ei[e], d = ei[E + e];
    float al = lrelu(a_src[(size_t)s * 4 + h] + a_dst[(size_t)d * 4 + h]);
    att_out[idx] = __expf(al - mfin[(size_t)d * 4 + h]) / (lfin[(size_t)d * 4 + h] + 1e-16f);
}

// ---------------- launcher ----------------
extern "C" void kernel_launch(void* const* d_in, const int* in_sizes, int n_in,
                              void* d_out, int out_size, void* d_ws, size_t ws_size,
                              hipStream_t stream) {
    const float* x     = (const float*)d_in[0];  // fp32 [N,256]
    const int*   ei    = (const int*)d_in[1];    // int32 [2,E]
    const float* W     = (const float*)d_in[2];  // fp32 [256,256]
    const float* att_s = (const float*)d_in[3];  // fp32 [4,64]
    const float* att_d = (const float*)d_in[4];  // fp32 [4,64]

    const int N = in_sizes[0] / IN_CH;   // 50000
    const int E = in_sizes[1] / 2;       // 800000

    char* ws = (char*)d_ws;
    size_t off = 0;
    float*          xh    = (float*)(ws + off);          off += (size_t)N * HC * 4;
    unsigned short* wt_hi = (unsigned short*)(ws + off); off += (size_t)IN_CH * HC * 2;
    unsigned short* wt_lo = (unsigned short*)(ws + off); off += (size_t)IN_CH * HC * 2;
    float* a_src = (float*)(ws + off); off += (size_t)N * H_HEADS * 4;
    float* a_dst = (float*)(ws + off); off += (size_t)N * H_HEADS * 4;
    float* mfin  = (float*)(ws + off); off += (size_t)N * H_HEADS * 4;
    float* lfin  = (float*)(ws + off); off += (size_t)N * H_HEADS * 4;
    int* rowptr  = (int*)(ws + off); off += (size_t)N * 4;
    int* cursor  = (int*)(ws + off); off += (size_t)N * 4;
    int* csr_src = (int*)(ws + off); off += (size_t)E * 4;
    size_t zoff = off;  // zero-init region
    int* deg     = (int*)(ws + off); off += (size_t)N * 4;

    float* out     = (float*)d_out;            // [N, 256] fp32
    float* out_att = out + (size_t)N * HC;     // [E, 4]   fp32

    hipMemsetAsync(ws + zoff, 0, off - zoff, stream);  // deg only

    prep_w<<<256, 256, 0, stream>>>(W, wt_hi, wt_lo);
    gemm_xh<<<dim3((N + 63) / 64, 4), 256, 0, stream>>>(x, wt_hi, wt_lo, xh, N);
    node_attn<<<(N + 3) / 4, 256, 0, stream>>>(xh, att_s, att_d, a_src, a_dst, N);
    deg_count<<<(E + 255) / 256, 256, 0, stream>>>(ei, deg, E);
    scan_rowptr<<<1, SCAN_T, 0, stream>>>(deg, rowptr, cursor, N);
    fill_csr<<<(E + 255) / 256, 256, 0, stream>>>(ei, cursor, csr_src, E);
    gat_gather<<<(N + 3) / 4, 256, 0, stream>>>(csr_src, rowptr, deg, a_src, a_dst,
                                                xh, out, mfin, lfin, N);
    att_edge<<<(E * 4 + 255) / 256, 256, 0, stream>>>(ei, a_src, a_dst, mfin, lfin,
                                                      out_att, E * 4);
}

// Round 5
// 558.969 us; speedup vs baseline: 5.7105x; 1.0283x over previous
//
#include <hip/hip_runtime.h>
#include <math.h>

// ---------------- constants (shapes fixed by the reference) ----------------
#define IN_CH   256
#define HC      256   // H*C
#define H_HEADS 4
#define NEG_SLOPE 0.2f
#define SCAN_T  1024

typedef __attribute__((ext_vector_type(8))) short short8;
typedef __attribute__((ext_vector_type(4))) short short4v;
typedef __attribute__((ext_vector_type(4))) float float4v;

// ---------------- helpers ----------------
__device__ __forceinline__ float bf2f(unsigned short b) {
    return __uint_as_float(((unsigned)b) << 16);
}
__device__ __forceinline__ unsigned short f2bf(float f) {
    unsigned u = __float_as_uint(f);
    u += 0x7fffu + ((u >> 16) & 1u);    // round-to-nearest-even
    return (unsigned short)(u >> 16);
}
__device__ __forceinline__ float lrelu(float a) {
    return a >= 0.f ? a : NEG_SLOPE * a;
}

// ---------------- kernels ----------------

// W (fp32, [256k x 256c] row-major) -> transposed bf16 hi/lo pair (wt[c][k])
__global__ void prep_w(const float* __restrict__ w,
                       unsigned short* __restrict__ wt_hi,
                       unsigned short* __restrict__ wt_lo) {
    int idx = blockIdx.x * 256 + threadIdx.x;   // 65536 total
    int k = idx >> 8, c = idx & 255;
    float v = w[idx];
    unsigned short hi = f2bf(v);
    unsigned short lo = f2bf(v - bf2f(hi));
    wt_hi[(size_t)c * 256 + k] = hi;
    wt_lo[(size_t)c * 256 + k] = lo;
}

// xh = x @ W, bf16 hi/lo split (3 MFMAs, rel err ~2^-16), 64x256 tile per block:
// each block computes ALL 4 column tiles so x is split once and read once.
// Column tile cb == head cb (C=64), so the epilogue computes COMPLETE
// a_src[n,cb]/a_dst[n,cb] dots via in-quad shfl reduction (node_attn fused).
// xh is stored bf16 (downstream gather only needs bf16 precision).
__global__ __launch_bounds__(256) void gemm_xh(const float* __restrict__ x,
                                               const unsigned short* __restrict__ wt_hi,
                                               const unsigned short* __restrict__ wt_lo,
                                               const float* __restrict__ att_s,
                                               const float* __restrict__ att_d,
                                               unsigned short* __restrict__ xh_bf,
                                               float* __restrict__ a_src,
                                               float* __restrict__ a_dst, int N) {
    int wave = threadIdx.x >> 6;
    int lane = threadIdx.x & 63;
    int quad = lane >> 4;
    int l16  = lane & 15;
    int rb = blockIdx.x * 64 + wave * 16;

    float4v acc[4][4];   // [cb][ct]
#pragma unroll
    for (int cb = 0; cb < 4; ++cb)
#pragma unroll
        for (int ct = 0; ct < 4; ++ct) acc[cb][ct] = (float4v){0.f, 0.f, 0.f, 0.f};

    int arow = rb + l16;                // A[m=lane&15][k=quad*8+j]
    if (arow >= N) arow = N - 1;        // clamp (stores guarded below)
    const float* xrow = x + (size_t)arow * IN_CH;

    for (int k0 = 0; k0 < IN_CH; k0 += 32) {
        float4v xa = *(const float4v*)(xrow + k0 + quad * 8);
        float4v xb = *(const float4v*)(xrow + k0 + quad * 8 + 4);
        short8 a_hi, a_lo;
#pragma unroll
        for (int j = 0; j < 4; ++j) {
            unsigned short h0 = f2bf(xa[j]);
            a_hi[j]     = (short)h0;
            a_lo[j]     = (short)f2bf(xa[j] - bf2f(h0));
            unsigned short h1 = f2bf(xb[j]);
            a_hi[4 + j] = (short)h1;
            a_lo[4 + j] = (short)f2bf(xb[j] - bf2f(h1));
        }
#pragma unroll
        for (int cb = 0; cb < 4; ++cb) {
#pragma unroll
            for (int ct = 0; ct < 4; ++ct) {
                int col = cb * 64 + ct * 16 + l16;   // B[k][n] from W^T[col][k]
                const size_t bo = (size_t)col * IN_CH + k0 + quad * 8;
                short8 bh = *(const short8*)(wt_hi + bo);
                short8 bl = *(const short8*)(wt_lo + bo);
                acc[cb][ct] = __builtin_amdgcn_mfma_f32_16x16x32_bf16(a_lo, bh, acc[cb][ct], 0, 0, 0);
                acc[cb][ct] = __builtin_amdgcn_mfma_f32_16x16x32_bf16(a_hi, bl, acc[cb][ct], 0, 0, 0);
                acc[cb][ct] = __builtin_amdgcn_mfma_f32_16x16x32_bf16(a_hi, bh, acc[cb][ct], 0, 0, 0);
            }
        }
    }

    // Epilogue. C/D: row = quad*4 + r, col = ct*16 + l16 (within head cb).
#pragma unroll
    for (int cb = 0; cb < 4; ++cb) {
        float ps[4] = {0.f, 0.f, 0.f, 0.f};
        float pd[4] = {0.f, 0.f, 0.f, 0.f};
#pragma unroll
        for (int ct = 0; ct < 4; ++ct) {
            float as_c = att_s[cb * 64 + ct * 16 + l16];
            float ad_c = att_d[cb * 64 + ct * 16 + l16];
#pragma unroll
            for (int r = 0; r < 4; ++r) {
                float v = acc[cb][ct][r];
                int grow = rb + quad * 4 + r;
                if (grow < N)
                    xh_bf[(size_t)grow * HC + cb * 64 + ct * 16 + l16] = f2bf(v);
                ps[r] += v * as_c;
                pd[r] += v * ad_c;
            }
        }
#pragma unroll
        for (int off = 1; off < 16; off <<= 1) {
#pragma unroll
            for (int r = 0; r < 4; ++r) {
                ps[r] += __shfl_xor(ps[r], off);
                pd[r] += __shfl_xor(pd[r], off);
            }
        }
        if (l16 == 0) {
#pragma unroll
            for (int r = 0; r < 4; ++r) {
                int grow = rb + quad * 4 + r;
                if (grow < N) {
                    a_src[(size_t)grow * 4 + cb] = ps[r];
                    a_dst[(size_t)grow * 4 + cb] = pd[r];
                }
            }
        }
    }
}

// degree histogram over dst
__global__ __launch_bounds__(256) void deg_count(const int* __restrict__ ei,
                                                 int* __restrict__ deg, int E) {
    int e = blockIdx.x * 256 + threadIdx.x;
    if (e >= E) return;
    atomicAdd(deg + ei[E + e], 1);
}

// single-block exclusive scan of deg[N] -> rowptr, cursor
__global__ __launch_bounds__(SCAN_T) void scan_rowptr(const int* __restrict__ deg,
                                                      int* __restrict__ rowptr,
                                                      int* __restrict__ cursor, int N) {
    __shared__ int part[SCAN_T];
    int t = threadIdx.x;
    int chunk = (N + SCAN_T - 1) / SCAN_T;
    int lo = t * chunk, hi = min(lo + chunk, N);
    int s = 0;
    for (int i = lo; i < hi; ++i) s += deg[i];
    part[t] = s;
    __syncthreads();
    for (int off = 1; off < SCAN_T; off <<= 1) {
        int tmp = (t >= off) ? part[t - off] : 0;
        __syncthreads();
        part[t] += tmp;
        __syncthreads();
    }
    int running = part[t] - s;   // exclusive prefix of this chunk
    for (int i = lo; i < hi; ++i) {
        rowptr[i] = running;
        cursor[i] = running;
        running += deg[i];
    }
}

// fill CSR: csr_src[slot] = src id, slots allocated per-dst via cursor atomics
__global__ __launch_bounds__(256) void fill_csr(const int* __restrict__ ei,
                                                int* __restrict__ cursor,
                                                int* __restrict__ csr_src, int E) {
    int e = blockIdx.x * 256 + threadIdx.x;
    if (e >= E) return;
    int s = ei[e], d = ei[E + e];
    int slot = atomicAdd(cursor + d, 1);
    csr_src[slot] = s;
}

// one wave per dst node: online-softmax gather over incoming edges (bf16 xh).
// lane owns flat channels [lane*4, lane*4+4); head h = lane>>4.
__global__ __launch_bounds__(256) void gat_gather(const int* __restrict__ csr_src,
                                                  const int* __restrict__ rowptr,
                                                  const int* __restrict__ deg,
                                                  const float* __restrict__ a_src,
                                                  const float* __restrict__ a_dst,
                                                  const unsigned short* __restrict__ xh_bf,
                                                  float* __restrict__ out,
                                                  float* __restrict__ mfin,
                                                  float* __restrict__ lfin, int N) {
    int wave = threadIdx.x >> 6, lane = threadIdx.x & 63;
    int d = blockIdx.x * 4 + wave;
    if (d >= N) return;
    int h = lane >> 4;
    int start = rowptr[d], cnt = deg[d];
    float adst = a_dst[(size_t)d * 4 + h];

    float m = -INFINITY, l = 0.f;
    float4v acc = {0.f, 0.f, 0.f, 0.f};

    // double-buffered prefetch of (src, a_src, xh row)
    int s_n = 0; float as_n = 0.f; short4v xv_n = {};
    if (cnt > 0) {
        s_n  = csr_src[start];
        as_n = a_src[(size_t)s_n * 4 + h];
        xv_n = *(const short4v*)(xh_bf + (size_t)s_n * HC + lane * 4);
    }
    for (int i = 0; i < cnt; ++i) {
        float as_c = as_n; short4v xv = xv_n;
        if (i + 1 < cnt) {
            s_n  = csr_src[start + i + 1];
            as_n = a_src[(size_t)s_n * 4 + h];
            xv_n = *(const short4v*)(xh_bf + (size_t)s_n * HC + lane * 4);
        }
        float al = lrelu(as_c + adst);
        float mn = fmaxf(m, al);
        float scale = __expf(m - mn);   // first iter: exp(-inf)=0
        float p     = __expf(al - mn);
        l = l * scale + p;
#pragma unroll
        for (int j = 0; j < 4; ++j)
            acc[j] = acc[j] * scale + p * bf2f((unsigned short)xv[j]);
        m = mn;
    }
    float inv = 1.f / (l + 1e-16f);
    float4v o = {acc[0] * inv, acc[1] * inv, acc[2] * inv, acc[3] * inv};
    *(float4v*)(out + (size_t)d * HC + lane * 4) = o;
    if ((lane & 15) == 0) {
        mfin[(size_t)d * 4 + h] = m;
        lfin[(size_t)d * 4 + h] = l;
    }
}

// att[e,:] = exp(alpha - m[d,:]) / (l[d,:] + eps); one thread per edge, float4 I/O
__global__ __launch_bounds__(256) void att_edge(const int* __restrict__ ei,
                                                const float* __restrict__ a_src,
                                                const float* __restrict__ a_dst,
                                                const float* __restrict__ mfin,
                                                const float* __restrict__ lfin,
                                                float* __restrict__ att_out, int E) {
    int e = blockIdx.x * 256 + threadIdx.x;
    if (e >= E) return;
    int s = ei[e], d = ei[E + e];
    float4v as = *(const float4v*)(a_src + (size_t)s * 4);
    float4v ad = *(const float4v*)(a_dst + (size_t)d * 4);
    float4v mm = *(const float4v*)(mfin + (size_t)d * 4);
    float4v ll = *(const float4v*)(lfin + (size_t)d * 4);
    float4v o;
#pragma unroll
    for (int h = 0; h < 4; ++h)
        o[h] = __expf(lrelu(as[h] + ad[h]) - mm[h]) / (ll[h] + 1e-16f);
    *(float4v*)(att_out + (size_t)e * 4) = o;
}

// ---------------- launcher ----------------
extern "C" void kernel_launch(void* const* d_in, const int* in_sizes, int n_in,
                              void* d_out, int out_size, void* d_ws, size_t ws_size,
                              hipStream_t stream) {
    const float* x     = (const float*)d_in[0];  // fp32 [N,256]
    const int*   ei    = (const int*)d_in[1];    // int32 [2,E]
    const float* W     = (const float*)d_in[2];  // fp32 [256,256]
    const float* att_s = (const float*)d_in[3];  // fp32 [4,64]
    const float* att_d = (const float*)d_in[4];  // fp32 [4,64]

    const int N = in_sizes[0] / IN_CH;   // 50000
    const int E = in_sizes[1] / 2;       // 800000

    char* ws = (char*)d_ws;
    size_t off = 0;
    unsigned short* xh_bf = (unsigned short*)(ws + off); off += (size_t)N * HC * 2;
    unsigned short* wt_hi = (unsigned short*)(ws + off); off += (size_t)IN_CH * HC * 2;
    unsigned short* wt_lo = (unsigned short*)(ws + off); off += (size_t)IN_CH * HC * 2;
    float* a_src = (float*)(ws + off); off += (size_t)N * H_HEADS * 4;
    float* a_dst = (float*)(ws + off); off += (size_t)N * H_HEADS * 4;
    float* mfin  = (float*)(ws + off); off += (size_t)N * H_HEADS * 4;
    float* lfin  = (float*)(ws + off); off += (size_t)N * H_HEADS * 4;
    int* rowptr  = (int*)(ws + off); off += (size_t)N * 4;
    int* cursor  = (int*)(ws + off); off += (size_t)N * 4;
    int* csr_src = (int*)(ws + off); off += (size_t)E * 4;
    size_t zoff = off;  // zero-init region
    int* deg     = (int*)(ws + off); off += (size_t)N * 4;

    float* out     = (float*)d_out;            // [N, 256] fp32
    float* out_att = out + (size_t)N * HC;     // [E, 4]   fp32

    hipMemsetAsync(ws + zoff, 0, off - zoff, stream);  // deg only

    prep_w<<<256, 256, 0, stream>>>(W, wt_hi, wt_lo);
    gemm_xh<<<(N + 63) / 64, 256, 0, stream>>>(x, wt_hi, wt_lo, att_s, att_d,
                                               xh_bf, a_src, a_dst, N);
    deg_count<<<(E + 255) / 256, 256, 0, stream>>>(ei, deg, E);
    scan_rowptr<<<1, SCAN_T, 0, stream>>>(deg, rowptr, cursor, N);
    fill_csr<<<(E + 255) / 256, 256, 0, stream>>>(ei, cursor, csr_src, E);
    gat_gather<<<(N + 3) / 4, 256, 0, stream>>>(csr_src, rowptr, deg, a_src, a_dst,
                                                xh_bf, out, mfin, lfin, N);
    att_edge<<<(E + 255) / 256, 256, 0, stream>>>(ei, a_src, a_dst, mfin, lfin,
                                                  out_att, E);
}

// Round 6
// 544.684 us; speedup vs baseline: 5.8602x; 1.0262x over previous
//
#include <hip/hip_runtime.h>
#include <math.h>

// ---------------- constants (shapes fixed by the reference) ----------------
#define IN_CH   256
#define HC      256   // H*C
#define H_HEADS 4
#define NEG_SLOPE 0.2f
#define SCAN_T  1024

typedef __attribute__((ext_vector_type(8))) short short8;
typedef __attribute__((ext_vector_type(4))) short short4v;
typedef __attribute__((ext_vector_type(4))) float float4v;

// ---------------- helpers ----------------
__device__ __forceinline__ float bf2f(unsigned short b) {
    return __uint_as_float(((unsigned)b) << 16);
}
__device__ __forceinline__ unsigned short f2bf(float f) {
    unsigned u = __float_as_uint(f);
    u += 0x7fffu + ((u >> 16) & 1u);    // round-to-nearest-even
    return (unsigned short)(u >> 16);
}
__device__ __forceinline__ float lrelu(float a) {
    return a >= 0.f ? a : NEG_SLOPE * a;
}

// ---------------- kernels ----------------

// W (fp32, [256k x 256c] row-major) -> transposed bf16 hi/lo pair (wt[c][k])
__global__ void prep_w(const float* __restrict__ w,
                       unsigned short* __restrict__ wt_hi,
                       unsigned short* __restrict__ wt_lo) {
    int idx = blockIdx.x * 256 + threadIdx.x;   // 65536 total
    int k = idx >> 8, c = idx & 255;
    float v = w[idx];
    unsigned short hi = f2bf(v);
    unsigned short lo = f2bf(v - bf2f(hi));
    wt_hi[(size_t)c * 256 + k] = hi;
    wt_lo[(size_t)c * 256 + k] = lo;
}

// x (fp32) -> bf16 hi/lo split, streaming. Removes the fp32->bf16 VALU chain
// from the gemm inner loop (it becomes pure short8-load -> MFMA).
__global__ __launch_bounds__(256) void prep_x(const float* __restrict__ x,
                                              unsigned short* __restrict__ x_hi,
                                              unsigned short* __restrict__ x_lo,
                                              int total4) {
    int i = blockIdx.x * 256 + threadIdx.x;
    if (i >= total4) return;
    float4v v = ((const float4v*)x)[i];
    short4v hi, lo;
#pragma unroll
    for (int j = 0; j < 4; ++j) {
        unsigned short h = f2bf(v[j]);
        hi[j] = (short)h;
        lo[j] = (short)f2bf(v[j] - bf2f(h));
    }
    ((short4v*)x_hi)[i] = hi;
    ((short4v*)x_lo)[i] = lo;
}

// xh = x @ W, bf16 hi/lo split (3 MFMAs, rel err ~2^-16).
// Geometry: grid (N/64, 4 heads); per-wave 16 rows x 64 cols (acc[4] = 16 VGPRs,
// small footprint -> high occupancy; 3128 blocks). grid.y == head cb, so the
// epilogue computes COMPLETE a_src[n,cb]/a_dst[n,cb] (node_attn fused).
// xh stored bf16 (downstream gather is bf16-precision).
__global__ __launch_bounds__(256) void gemm_xh(const unsigned short* __restrict__ x_hi,
                                               const unsigned short* __restrict__ x_lo,
                                               const unsigned short* __restrict__ wt_hi,
                                               const unsigned short* __restrict__ wt_lo,
                                               const float* __restrict__ att_s,
                                               const float* __restrict__ att_d,
                                               unsigned short* __restrict__ xh_bf,
                                               float* __restrict__ a_src,
                                               float* __restrict__ a_dst, int N) {
    int wave = threadIdx.x >> 6;
    int lane = threadIdx.x & 63;
    int quad = lane >> 4;
    int l16  = lane & 15;
    int rb = blockIdx.x * 64 + wave * 16;
    int cb = blockIdx.y;                 // head index, 64 cols

    float4v acc[4] = {};
    int arow = rb + l16;                 // A[m=lane&15][k=quad*8+j]
    if (arow >= N) arow = N - 1;         // clamp (stores guarded below)
    const unsigned short* xh_row = x_hi + (size_t)arow * IN_CH;
    const unsigned short* xl_row = x_lo + (size_t)arow * IN_CH;

#pragma unroll
    for (int k0 = 0; k0 < IN_CH; k0 += 32) {
        short8 a_hi = *(const short8*)(xh_row + k0 + quad * 8);
        short8 a_lo = *(const short8*)(xl_row + k0 + quad * 8);
#pragma unroll
        for (int ct = 0; ct < 4; ++ct) {
            int col = cb * 64 + ct * 16 + l16;   // B[k][n] from W^T[col][k]
            const size_t bo = (size_t)col * IN_CH + k0 + quad * 8;
            short8 bh = *(const short8*)(wt_hi + bo);
            short8 bl = *(const short8*)(wt_lo + bo);
            acc[ct] = __builtin_amdgcn_mfma_f32_16x16x32_bf16(a_lo, bh, acc[ct], 0, 0, 0);
            acc[ct] = __builtin_amdgcn_mfma_f32_16x16x32_bf16(a_hi, bl, acc[ct], 0, 0, 0);
            acc[ct] = __builtin_amdgcn_mfma_f32_16x16x32_bf16(a_hi, bh, acc[ct], 0, 0, 0);
        }
    }

    // Epilogue. C/D: row = quad*4 + r, col = ct*16 + l16 (within head cb).
    float ps[4] = {0.f, 0.f, 0.f, 0.f};
    float pd[4] = {0.f, 0.f, 0.f, 0.f};
#pragma unroll
    for (int ct = 0; ct < 4; ++ct) {
        float as_c = att_s[cb * 64 + ct * 16 + l16];
        float ad_c = att_d[cb * 64 + ct * 16 + l16];
#pragma unroll
        for (int r = 0; r < 4; ++r) {
            float v = acc[ct][r];
            int grow = rb + quad * 4 + r;
            if (grow < N)
                xh_bf[(size_t)grow * HC + cb * 64 + ct * 16 + l16] = f2bf(v);
            ps[r] += v * as_c;
            pd[r] += v * ad_c;
        }
    }
#pragma unroll
    for (int off = 1; off < 16; off <<= 1) {
#pragma unroll
        for (int r = 0; r < 4; ++r) {
            ps[r] += __shfl_xor(ps[r], off);
            pd[r] += __shfl_xor(pd[r], off);
        }
    }
    if (l16 == 0) {
#pragma unroll
        for (int r = 0; r < 4; ++r) {
            int grow = rb + quad * 4 + r;
            if (grow < N) {
                a_src[(size_t)grow * 4 + cb] = ps[r];
                a_dst[(size_t)grow * 4 + cb] = pd[r];
            }
        }
    }
}

// degree histogram over dst
__global__ __launch_bounds__(256) void deg_count(const int* __restrict__ ei,
                                                 int* __restrict__ deg, int E) {
    int e = blockIdx.x * 256 + threadIdx.x;
    if (e >= E) return;
    atomicAdd(deg + ei[E + e], 1);
}

// single-block exclusive scan of deg[N] -> rowptr, cursor
__global__ __launch_bounds__(SCAN_T) void scan_rowptr(const int* __restrict__ deg,
                                                      int* __restrict__ rowptr,
                                                      int* __restrict__ cursor, int N) {
    __shared__ int part[SCAN_T];
    int t = threadIdx.x;
    int chunk = (N + SCAN_T - 1) / SCAN_T;
    int lo = t * chunk, hi = min(lo + chunk, N);
    int s = 0;
    for (int i = lo; i < hi; ++i) s += deg[i];
    part[t] = s;
    __syncthreads();
    for (int off = 1; off < SCAN_T; off <<= 1) {
        int tmp = (t >= off) ? part[t - off] : 0;
        __syncthreads();
        part[t] += tmp;
        __syncthreads();
    }
    int running = part[t] - s;   // exclusive prefix of this chunk
    for (int i = lo; i < hi; ++i) {
        rowptr[i] = running;
        cursor[i] = running;
        running += deg[i];
    }
}

// fill CSR: csr_src[slot] = src id, slots allocated per-dst via cursor atomics
__global__ __launch_bounds__(256) void fill_csr(const int* __restrict__ ei,
                                                int* __restrict__ cursor,
                                                int* __restrict__ csr_src, int E) {
    int e = blockIdx.x * 256 + threadIdx.x;
    if (e >= E) return;
    int s = ei[e], d = ei[E + e];
    int slot = atomicAdd(cursor + d, 1);
    csr_src[slot] = s;
}

// one wave per dst node: online-softmax gather over incoming edges (bf16 xh).
// lane owns flat channels [lane*4, lane*4+4); head h = lane>>4.
// Depth-2 pipeline: src-ids fetched 2 edges ahead, edge data 1 edge ahead.
__global__ __launch_bounds__(256) void gat_gather(const int* __restrict__ csr_src,
                                                  const int* __restrict__ rowptr,
                                                  const int* __restrict__ deg,
                                                  const float* __restrict__ a_src,
                                                  const float* __restrict__ a_dst,
                                                  const unsigned short* __restrict__ xh_bf,
                                                  float* __restrict__ out,
                                                  float* __restrict__ mfin,
                                                  float* __restrict__ lfin, int N) {
    int wave = threadIdx.x >> 6, lane = threadIdx.x & 63;
    int d = blockIdx.x * 4 + wave;
    if (d >= N) return;
    int h = lane >> 4;
    int start = rowptr[d], cnt = deg[d];
    float adst = a_dst[(size_t)d * 4 + h];

    float m = -INFINITY, l = 0.f;
    float4v acc = {0.f, 0.f, 0.f, 0.f};

    // pipeline state: sA = src of edge i+1, sB = src of edge i+2
    // (as_c/xv_c = data for edge i, as_n/xv_n = data for edge i+1)
    int sA = 0, sB = 0;
    float as_c = 0.f, as_n = 0.f;
    short4v xv_c = {}, xv_n = {};
    if (cnt > 0) {
        int s0 = csr_src[start];
        as_c = a_src[(size_t)s0 * 4 + h];
        xv_c = *(const short4v*)(xh_bf + (size_t)s0 * HC + lane * 4);
    }
    if (cnt > 1) sA = csr_src[start + 1];
    if (cnt > 2) sB = csr_src[start + 2];
    for (int i = 0; i < cnt; ++i) {
        // issue data loads for edge i+1 and src-id load for edge i+3
        if (i + 1 < cnt) {
            as_n = a_src[(size_t)sA * 4 + h];
            xv_n = *(const short4v*)(xh_bf + (size_t)sA * HC + lane * 4);
        }
        int sC = (i + 3 < cnt) ? csr_src[start + i + 3] : 0;
        // compute edge i
        float al = lrelu(as_c + adst);
        float mn = fmaxf(m, al);
        float scale = __expf(m - mn);   // first iter: exp(-inf)=0
        float p     = __expf(al - mn);
        l = l * scale + p;
#pragma unroll
        for (int j = 0; j < 4; ++j)
            acc[j] = acc[j] * scale + p * bf2f((unsigned short)xv_c[j]);
        m = mn;
        // rotate pipeline
        as_c = as_n; xv_c = xv_n;
        sA = sB; sB = sC;
    }
    float inv = 1.f / (l + 1e-16f);
    float4v o = {acc[0] * inv, acc[1] * inv, acc[2] * inv, acc[3] * inv};
    *(float4v*)(out + (size_t)d * HC + lane * 4) = o;
    if ((lane & 15) == 0) {
        mfin[(size_t)d * 4 + h] = m;
        lfin[(size_t)d * 4 + h] = l;
    }
}

// att[e,:] = exp(alpha - m[d,:]) / (l[d,:] + eps); one thread per edge, float4 I/O
__global__ __launch_bounds__(256) void att_edge(const int* __restrict__ ei,
                                                const float* __restrict__ a_src,
                                                const float* __restrict__ a_dst,
                                                const float* __restrict__ mfin,
                                                const float* __restrict__ lfin,
                                                float* __restrict__ att_out, int E) {
    int e = blockIdx.x * 256 + threadIdx.x;
    if (e >= E) return;
    int s = ei[e], d = ei[E + e];
    float4v as = *(const float4v*)(a_src + (size_t)s * 4);
    float4v ad = *(const float4v*)(a_dst + (size_t)d * 4);
    float4v mm = *(const float4v*)(mfin + (size_t)d * 4);
    float4v ll = *(const float4v*)(lfin + (size_t)d * 4);
    float4v o;
#pragma unroll
    for (int h = 0; h < 4; ++h)
        o[h] = __expf(lrelu(as[h] + ad[h]) - mm[h]) / (ll[h] + 1e-16f);
    *(float4v*)(att_out + (size_t)e * 4) = o;
}

// ---------------- launcher ----------------
extern "C" void kernel_launch(void* const* d_in, const int* in_sizes, int n_in,
                              void* d_out, int out_size, void* d_ws, size_t ws_size,
                              hipStream_t stream) {
    const float* x     = (const float*)d_in[0];  // fp32 [N,256]
    const int*   ei    = (const int*)d_in[1];    // int32 [2,E]
    const float* W     = (const float*)d_in[2];  // fp32 [256,256]
    const float* att_s = (const float*)d_in[3];  // fp32 [4,64]
    const float* att_d = (const float*)d_in[4];  // fp32 [4,64]

    const int N = in_sizes[0] / IN_CH;   // 50000
    const int E = in_sizes[1] / 2;       // 800000

    char* ws = (char*)d_ws;
    size_t off = 0;
    unsigned short* xh_bf = (unsigned short*)(ws + off); off += (size_t)N * HC * 2;
    unsigned short* x_hi  = (unsigned short*)(ws + off); off += (size_t)N * IN_CH * 2;
    unsigned short* x_lo  = (unsigned short*)(ws + off); off += (size_t)N * IN_CH * 2;
    unsigned short* wt_hi = (unsigned short*)(ws + off); off += (size_t)IN_CH * HC * 2;
    unsigned short* wt_lo = (unsigned short*)(ws + off); off += (size_t)IN_CH * HC * 2;
    float* a_src = (float*)(ws + off); off += (size_t)N * H_HEADS * 4;
    float* a_dst = (float*)(ws + off); off += (size_t)N * H_HEADS * 4;
    float* mfin  = (float*)(ws + off); off += (size_t)N * H_HEADS * 4;
    float* lfin  = (float*)(ws + off); off += (size_t)N * H_HEADS * 4;
    int* rowptr  = (int*)(ws + off); off += (size_t)N * 4;
    int* cursor  = (int*)(ws + off); off += (size_t)N * 4;
    int* csr_src = (int*)(ws + off); off += (size_t)E * 4;
    size_t zoff = off;  // zero-init region
    int* deg     = (int*)(ws + off); off += (size_t)N * 4;

    float* out     = (float*)d_out;            // [N, 256] fp32
    float* out_att = out + (size_t)N * HC;     // [E, 4]   fp32

    hipMemsetAsync(ws + zoff, 0, off - zoff, stream);  // deg only

    prep_w<<<256, 256, 0, stream>>>(W, wt_hi, wt_lo);
    prep_x<<<(N * IN_CH / 4 + 255) / 256, 256, 0, stream>>>(x, x_hi, x_lo, N * IN_CH / 4);
    deg_count<<<(E + 255) / 256, 256, 0, stream>>>(ei, deg, E);
    gemm_xh<<<dim3((N + 63) / 64, 4), 256, 0, stream>>>(x_hi, x_lo, wt_hi, wt_lo,
                                                        att_s, att_d, xh_bf,
                                                        a_src, a_dst, N);
    scan_rowptr<<<1, SCAN_T, 0, stream>>>(deg, rowptr, cursor, N);
    fill_csr<<<(E + 255) / 256, 256, 0, stream>>>(ei, cursor, csr_src, E);
    gat_gather<<<(N + 3) / 4, 256, 0, stream>>>(csr_src, rowptr, deg, a_src, a_dst,
                                                xh_bf, out, mfin, lfin, N);
    att_edge<<<(E + 255) / 256, 256, 0, stream>>>(ei, a_src, a_dst, mfin, lfin,
                                                  out_att, E);
}

// Round 8
// 450.116 us; speedup vs baseline: 7.0915x; 1.2101x over previous
//
#include <hip/hip_runtime.h>
#include <math.h>

// ---------------- constants (shapes fixed by the reference) ----------------
#define IN_CH   256
#define HC      256   // H*C
#define H_HEADS 4
#define NEG_SLOPE 0.2f
#define SCAN_T  1024

typedef __attribute__((ext_vector_type(8))) short short8;
typedef __attribute__((ext_vector_type(4))) short short4v;
typedef __attribute__((ext_vector_type(4))) float float4v;

// ---------------- helpers ----------------
__device__ __forceinline__ float bf2f(unsigned short b) {
    return __uint_as_float(((unsigned)b) << 16);
}
__device__ __forceinline__ unsigned short f2bf(float f) {
    unsigned u = __float_as_uint(f);
    u += 0x7fffu + ((u >> 16) & 1u);    // round-to-nearest-even
    return (unsigned short)(u >> 16);
}
__device__ __forceinline__ float lrelu(float a) {
    return a >= 0.f ? a : NEG_SLOPE * a;
}

// ---------------- kernels ----------------

// W (fp32, [256k x 256c] row-major) -> transposed bf16 (wt[c][k])
__global__ void prep_w(const float* __restrict__ w,
                       unsigned short* __restrict__ wt) {
    int idx = blockIdx.x * 256 + threadIdx.x;   // 65536 total
    int k = idx >> 8, c = idx & 255;
    wt[(size_t)c * 256 + k] = f2bf(w[idx]);
}

// x (fp32) -> bf16 hi/lo split, streaming.
__global__ __launch_bounds__(256) void prep_x(const float* __restrict__ x,
                                              unsigned short* __restrict__ x_hi,
                                              unsigned short* __restrict__ x_lo,
                                              int total4) {
    int i = blockIdx.x * 256 + threadIdx.x;
    if (i >= total4) return;
    float4v v = ((const float4v*)x)[i];
    short4v hi, lo;
#pragma unroll
    for (int j = 0; j < 4; ++j) {
        unsigned short h = f2bf(v[j]);
        hi[j] = (short)h;
        lo[j] = (short)f2bf(v[j] - bf2f(h));
    }
    ((short4v*)x_hi)[i] = hi;
    ((short4v*)x_lo)[i] = lo;
}

// xh = x @ W. Block = 16 rows x 256 cols (4 waves = 4 heads): x fetched ONCE.
// A-tile (16 rows x 256 k, hi+lo bf16 = 16 KB) staged to LDS via plain
// global-load -> ds_write_b128 (graph-capture-safe; round-7's
// global_load_lds variant diverged under graph replay). Chunk-transposed
// layout [kc][m]: slot q holds row (q&15), k-chunk (q>>4)&31; ds_read_b128
// A-fragments are 2-way bank-aliased (free). 2 MFMAs per fragment
// (a_hi*bh + a_lo*bh; a_hi*b_lo term ~6e-4, dropped).
// Epilogue fuses node_attn (complete per-head dots via 16-lane shfl).
__global__ __launch_bounds__(256) void gemm_xh(const unsigned short* __restrict__ x_hi,
                                               const unsigned short* __restrict__ x_lo,
                                               const unsigned short* __restrict__ wt,
                                               const float* __restrict__ att_s,
                                               const float* __restrict__ att_d,
                                               unsigned short* __restrict__ xh_bf,
                                               float* __restrict__ a_src,
                                               float* __restrict__ a_dst, int N) {
    __shared__ __attribute__((aligned(16))) unsigned char lds_a[16384];
    int tid  = threadIdx.x;
    int wave = tid >> 6;            // == head index
    int lane = tid & 63;
    int quad = lane >> 4;
    int l16  = lane & 15;
    int rb   = blockIdx.x * 16;

    // ---- stage A-tile: 1024 slots x 16 B; slots [0,512) hi, [512,1024) lo ----
#pragma unroll
    for (int pass = 0; pass < 4; ++pass) {
        int q    = pass * 256 + tid;
        int half = q >> 9;                      // 0 = hi, 1 = lo
        int s    = q & 511;
        int kc   = s >> 4;                      // 16-B chunk index (k/8)
        int m    = s & 15;                      // row within tile
        int grow = rb + m; if (grow >= N) grow = N - 1;
        const unsigned short* gp =
            (half ? x_lo : x_hi) + (size_t)grow * IN_CH + kc * 8;
        short8 v = *(const short8*)gp;
        *(short8*)(lds_a + (size_t)q * 16) = v;
    }
    __syncthreads();

    // ---- K-loop: 8 x { 2 ds_read_b128 + 4 x (1 B-load + 2 MFMA) } ----
    float4v acc[4] = {};
    const unsigned short* wt_base = wt + ((size_t)wave * 64 + l16) * IN_CH;
#pragma unroll
    for (int k0 = 0; k0 < 8; ++k0) {
        int kc   = k0 * 4 + quad;
        int slot = kc * 16 + l16;
        short8 a_hi = *(const short8*)(lds_a + slot * 16);
        short8 a_lo = *(const short8*)(lds_a + 8192 + slot * 16);
#pragma unroll
        for (int ct = 0; ct < 4; ++ct) {
            short8 bh = *(const short8*)(wt_base + (size_t)ct * 16 * IN_CH
                                         + k0 * 32 + quad * 8);
            acc[ct] = __builtin_amdgcn_mfma_f32_16x16x32_bf16(a_lo, bh, acc[ct], 0, 0, 0);
            acc[ct] = __builtin_amdgcn_mfma_f32_16x16x32_bf16(a_hi, bh, acc[ct], 0, 0, 0);
        }
    }

    // ---- epilogue: xh store + fused a_src/a_dst (head = wave) ----
    int cb = wave;
    float ps[4] = {0.f, 0.f, 0.f, 0.f};
    float pd[4] = {0.f, 0.f, 0.f, 0.f};
#pragma unroll
    for (int ct = 0; ct < 4; ++ct) {
        float as_c = att_s[cb * 64 + ct * 16 + l16];
        float ad_c = att_d[cb * 64 + ct * 16 + l16];
#pragma unroll
        for (int r = 0; r < 4; ++r) {
            float v = acc[ct][r];
            int grow = rb + quad * 4 + r;
            if (grow < N)
                xh_bf[(size_t)grow * HC + cb * 64 + ct * 16 + l16] = f2bf(v);
            ps[r] += v * as_c;
            pd[r] += v * ad_c;
        }
    }
#pragma unroll
    for (int off = 1; off < 16; off <<= 1) {
#pragma unroll
        for (int r = 0; r < 4; ++r) {
            ps[r] += __shfl_xor(ps[r], off);
            pd[r] += __shfl_xor(pd[r], off);
        }
    }
    if (l16 == 0) {
#pragma unroll
        for (int r = 0; r < 4; ++r) {
            int grow = rb + quad * 4 + r;
            if (grow < N) {
                a_src[(size_t)grow * 4 + cb] = ps[r];
                a_dst[(size_t)grow * 4 + cb] = pd[r];
            }
        }
    }
}

// degree histogram over dst
__global__ __launch_bounds__(256) void deg_count(const int* __restrict__ ei,
                                                 int* __restrict__ deg, int E) {
    int e = blockIdx.x * 256 + threadIdx.x;
    if (e >= E) return;
    atomicAdd(deg + ei[E + e], 1);
}

// single-block exclusive scan of deg[N] -> rowptr, cursor
__global__ __launch_bounds__(SCAN_T) void scan_rowptr(const int* __restrict__ deg,
                                                      int* __restrict__ rowptr,
                                                      int* __restrict__ cursor, int N) {
    __shared__ int part[SCAN_T];
    int t = threadIdx.x;
    int chunk = (N + SCAN_T - 1) / SCAN_T;
    int lo = t * chunk, hi = min(lo + chunk, N);
    int s = 0;
    for (int i = lo; i < hi; ++i) s += deg[i];
    part[t] = s;
    __syncthreads();
    for (int off = 1; off < SCAN_T; off <<= 1) {
        int tmp = (t >= off) ? part[t - off] : 0;
        __syncthreads();
        part[t] += tmp;
        __syncthreads();
    }
    int running = part[t] - s;   // exclusive prefix of this chunk
    for (int i = lo; i < hi; ++i) {
        rowptr[i] = running;
        cursor[i] = running;
        running += deg[i];
    }
}

// fill CSR: csr_src[slot] = src id, slots allocated per-dst via cursor atomics
__global__ __launch_bounds__(256) void fill_csr(const int* __restrict__ ei,
                                                int* __restrict__ cursor,
                                                int* __restrict__ csr_src, int E) {
    int e = blockIdx.x * 256 + threadIdx.x;
    if (e >= E) return;
    int s = ei[e], d = ei[E + e];
    int slot = atomicAdd(cursor + d, 1);
    csr_src[slot] = s;
}

// one wave per dst: online-softmax gather, UNROLL-2 (independent even/odd
// states merged at the end -> 2 xh rows in flight). Emits out row + packed
// per-dst {a_dst, m, 1/(l+eps)} (12 floats) for att_edge.
__global__ __launch_bounds__(256) void gat_gather(const int* __restrict__ csr_src,
                                                  const int* __restrict__ rowptr,
                                                  const int* __restrict__ deg,
                                                  const float* __restrict__ a_src,
                                                  const float* __restrict__ a_dst,
                                                  const unsigned short* __restrict__ xh_bf,
                                                  float* __restrict__ out,
                                                  float* __restrict__ pack, int N) {
    int wave = threadIdx.x >> 6, lane = threadIdx.x & 63;
    int d = blockIdx.x * 4 + wave;
    if (d >= N) return;
    int h = lane >> 4;
    int start = rowptr[d], cnt = deg[d];
    float adst = a_dst[(size_t)d * 4 + h];

    if (cnt == 0) {
        *(float4v*)(out + (size_t)d * HC + lane * 4) = (float4v){0.f, 0.f, 0.f, 0.f};
        if ((lane & 15) == 0) {   // write pack anyway: no poison ever readable
            pack[(size_t)d * 12 + h]     = adst;
            pack[(size_t)d * 12 + 4 + h] = 0.f;
            pack[(size_t)d * 12 + 8 + h] = 0.f;
        }
        return;
    }

    float mE = -INFINITY, lE = 0.f, mO = -INFINITY, lO = 0.f;
    float4v accE = {0.f, 0.f, 0.f, 0.f}, accO = {0.f, 0.f, 0.f, 0.f};

    int s2 = 0, s3 = 0;
    float asE = 0.f, asO = 0.f;
    short4v xvE = {}, xvO = {};
    {
        int s0 = csr_src[start];
        asE = a_src[(size_t)s0 * 4 + h];
        xvE = *(const short4v*)(xh_bf + (size_t)s0 * HC + lane * 4);
    }
    if (cnt > 1) {
        int s1 = csr_src[start + 1];
        asO = a_src[(size_t)s1 * 4 + h];
        xvO = *(const short4v*)(xh_bf + (size_t)s1 * HC + lane * 4);
    }
    if (cnt > 2) s2 = csr_src[start + 2];
    if (cnt > 3) s3 = csr_src[start + 3];

    for (int i = 0; i < cnt; i += 2) {
        // prefetch data for edges i+2,i+3; ids for i+4,i+5
        float asE_n = 0.f, asO_n = 0.f;
        short4v xvE_n = {}, xvO_n = {};
        if (i + 2 < cnt) {
            asE_n = a_src[(size_t)s2 * 4 + h];
            xvE_n = *(const short4v*)(xh_bf + (size_t)s2 * HC + lane * 4);
        }
        if (i + 3 < cnt) {
            asO_n = a_src[(size_t)s3 * 4 + h];
            xvO_n = *(const short4v*)(xh_bf + (size_t)s3 * HC + lane * 4);
        }
        int s4 = (i + 4 < cnt) ? csr_src[start + i + 4] : 0;
        int s5 = (i + 5 < cnt) ? csr_src[start + i + 5] : 0;
        // compute edge i (E state)
        {
            float al = lrelu(asE + adst);
            float mn = fmaxf(mE, al);
            float sc = __expf(mE - mn);
            float p  = __expf(al - mn);
            lE = lE * sc + p;
#pragma unroll
            for (int j = 0; j < 4; ++j)
                accE[j] = accE[j] * sc + p * bf2f((unsigned short)xvE[j]);
            mE = mn;
        }
        // compute edge i+1 (O state)
        if (i + 1 < cnt) {
            float al = lrelu(asO + adst);
            float mn = fmaxf(mO, al);
            float sc = __expf(mO - mn);
            float p  = __expf(al - mn);
            lO = lO * sc + p;
#pragma unroll
            for (int j = 0; j < 4; ++j)
                accO[j] = accO[j] * sc + p * bf2f((unsigned short)xvO[j]);
            mO = mn;
        }
        asE = asE_n; xvE = xvE_n; asO = asO_n; xvO = xvO_n;
        s2 = s4; s3 = s5;
    }
    // merge states (mE finite since cnt >= 1; empty O contributes 0)
    float mm = fmaxf(mE, mO);
    float sE = __expf(mE - mm), sO = __expf(mO - mm);
    float l  = lE * sE + lO * sO;
    float inv = 1.f / (l + 1e-16f);
    float4v o;
#pragma unroll
    for (int j = 0; j < 4; ++j) o[j] = (accE[j] * sE + accO[j] * sO) * inv;
    *(float4v*)(out + (size_t)d * HC + lane * 4) = o;
    if ((lane & 15) == 0) {
        pack[(size_t)d * 12 + h]     = adst;
        pack[(size_t)d * 12 + 4 + h] = mm;
        pack[(size_t)d * 12 + 8 + h] = inv;
    }
}

// att[e,:] = exp(lrelu(a_src[s]+a_dst[d]) - m[d]) * inv_l[d]; packed dst reads
__global__ __launch_bounds__(256) void att_edge(const int* __restrict__ ei,
                                                const float* __restrict__ a_src,
                                                const float* __restrict__ pack,
                                                float* __restrict__ att_out, int E) {
    int e = blockIdx.x * 256 + threadIdx.x;
    if (e >= E) return;
    int s = ei[e], d = ei[E + e];
    float4v as = *(const float4v*)(a_src + (size_t)s * 4);
    float4v ad = *(const float4v*)(pack + (size_t)d * 12);
    float4v mm = *(const float4v*)(pack + (size_t)d * 12 + 4);
    float4v gg = *(const float4v*)(pack + (size_t)d * 12 + 8);
    float4v o;
#pragma unroll
    for (int h = 0; h < 4; ++h)
        o[h] = __expf(lrelu(as[h] + ad[h]) - mm[h]) * gg[h];
    *(float4v*)(att_out + (size_t)e * 4) = o;
}

// ---------------- launcher ----------------
extern "C" void kernel_launch(void* const* d_in, const int* in_sizes, int n_in,
                              void* d_out, int out_size, void* d_ws, size_t ws_size,
                              hipStream_t stream) {
    const float* x     = (const float*)d_in[0];  // fp32 [N,256]
    const int*   ei    = (const int*)d_in[1];    // int32 [2,E]
    const float* W     = (const float*)d_in[2];  // fp32 [256,256]
    const float* att_s = (const float*)d_in[3];  // fp32 [4,64]
    const float* att_d = (const float*)d_in[4];  // fp32 [4,64]

    const int N = in_sizes[0] / IN_CH;   // 50000
    const int E = in_sizes[1] / 2;       // 800000

    char* ws = (char*)d_ws;
    size_t off = 0;
    unsigned short* xh_bf = (unsigned short*)(ws + off); off += (size_t)N * HC * 2;
    unsigned short* x_hi  = (unsigned short*)(ws + off); off += (size_t)N * IN_CH * 2;
    unsigned short* x_lo  = (unsigned short*)(ws + off); off += (size_t)N * IN_CH * 2;
    unsigned short* wt    = (unsigned short*)(ws + off); off += (size_t)IN_CH * HC * 2;
    float* a_src = (float*)(ws + off); off += (size_t)N * H_HEADS * 4;
    float* a_dst = (float*)(ws + off); off += (size_t)N * H_HEADS * 4;
    float* pack  = (float*)(ws + off); off += (size_t)N * 12 * 4;
    int* rowptr  = (int*)(ws + off); off += (size_t)N * 4;
    int* cursor  = (int*)(ws + off); off += (size_t)N * 4;
    int* csr_src = (int*)(ws + off); off += (size_t)E * 4;
    size_t zoff = off;  // zero-init region
    int* deg     = (int*)(ws + off); off += (size_t)N * 4;

    float* out     = (float*)d_out;            // [N, 256] fp32
    float* out_att = out + (size_t)N * HC;     // [E, 4]   fp32

    hipMemsetAsync(ws + zoff, 0, off - zoff, stream);  // deg only

    prep_w<<<256, 256, 0, stream>>>(W, wt);
    prep_x<<<(N * IN_CH / 4 + 255) / 256, 256, 0, stream>>>(x, x_hi, x_lo, N * IN_CH / 4);
    deg_count<<<(E + 255) / 256, 256, 0, stream>>>(ei, deg, E);
    gemm_xh<<<(N + 15) / 16, 256, 0, stream>>>(x_hi, x_lo, wt, att_s, att_d,
                                               xh_bf, a_src, a_dst, N);
    scan_rowptr<<<1, SCAN_T, 0, stream>>>(deg, rowptr, cursor, N);
    fill_csr<<<(E + 255) / 256, 256, 0, stream>>>(ei, cursor, csr_src, E);
    gat_gather<<<(N + 3) / 4, 256, 0, stream>>>(csr_src, rowptr, deg, a_src, a_dst,
                                                xh_bf, out, pack, N);
    att_edge<<<(E + 255) / 256, 256, 0, stream>>>(ei, a_src, pack, out_att, E);
}